// Round 9
// baseline (2635.774 us; speedup 1.0000x reference)
//
#include <hip/hip_runtime.h>
#include <hip/hip_bf16.h>

// ---------------------------------------------------------------------------
// IEGMN layer, MI355X round-9: barrier-free attention + 64-edge MLP blocks.
// ---------------------------------------------------------------------------

#define N_LIG   4096
#define N_REC   16384
#define E_LIG_N 65536
#define E_REC_N 262144
#define HD      256
#define ORIGD   64
#define EFD     16
#define NSIG    15
#define EIN     543
#define XP      552      // edge sX pitch (bf16 elems), 544 used
#define XPN     584      // node sX pitch, 576 used
#define XPP     264      // proj sX pitch, 256 used

typedef __bf16 bf16x8 __attribute__((ext_vector_type(8)));
typedef float  f32x4  __attribute__((ext_vector_type(4)));

__device__ __forceinline__ float lrelu(float x) { return x > 0.f ? x : 0.01f * x; }
__device__ __forceinline__ unsigned short f2bu(float f) {
    __hip_bfloat16 h = __float2bfloat16(f);
    return *reinterpret_cast<unsigned short*>(&h);
}

// ---------------------------------------------------------------------------
// MT x K x (NT*16) GEMM core, reg double-buffered. A: LDS rows (bf16, pitch).
// Wswz: fragment-ordered weights for NT consecutive 16-col groups.
template <int MT, int NT>
__device__ __forceinline__ void mfma_gemm(
    const unsigned short* sA, int pitch,
    const __hip_bfloat16* Wswz, int KS, int lane, f32x4 acc[MT][NT])
{
    const int col = lane & 15, quad = lane >> 4;
    const unsigned short* ap[MT];
    #pragma unroll
    for (int mt = 0; mt < MT; ++mt)
        ap[mt] = sA + (size_t)(mt * 16 + col) * pitch + quad * 8;
    const __hip_bfloat16* wp = Wswz + lane * 8;
    bf16x8 bc[NT], bn[NT], ac[MT], an[MT];
    #pragma unroll
    for (int nt = 0; nt < NT; ++nt)
        bc[nt] = *reinterpret_cast<const bf16x8*>(wp + (size_t)nt * KS * 512);
    #pragma unroll
    for (int mt = 0; mt < MT; ++mt)
        ac[mt] = *reinterpret_cast<const bf16x8*>(ap[mt]);
    for (int ks = 0; ks < KS; ++ks) {
        if (ks + 1 < KS) {
            #pragma unroll
            for (int nt = 0; nt < NT; ++nt)
                bn[nt] = *reinterpret_cast<const bf16x8*>(
                    wp + ((size_t)nt * KS + ks + 1) * 512);
            #pragma unroll
            for (int mt = 0; mt < MT; ++mt)
                an[mt] = *reinterpret_cast<const bf16x8*>(ap[mt] + (ks + 1) * 32);
        }
        #pragma unroll
        for (int nt = 0; nt < NT; ++nt)
            #pragma unroll
            for (int mt = 0; mt < MT; ++mt)
                acc[mt][nt] = __builtin_amdgcn_mfma_f32_16x16x32_bf16(
                    ac[mt], bc[nt], acc[mt][nt], 0, 0, 0);
        #pragma unroll
        for (int nt = 0; nt < NT; ++nt) bc[nt] = bn[nt];
        #pragma unroll
        for (int mt = 0; mt < MT; ++mt) ac[mt] = an[mt];
    }
}

// ---------------------------------------------------------------------------
__global__ void zero_kernel(float* __restrict__ p, int n) {
    int i = blockIdx.x * 256 + threadIdx.x;
    if (i < n) p[i] = 0.f;
}

// ---------------------------------------------------------------------------
__global__ void wt_swz(const float* __restrict__ src,
                       __hip_bfloat16* __restrict__ dst, int K, int KS) {
    const int g  = blockIdx.x / KS;
    const int ks = blockIdx.x % KS;
    for (int i = threadIdx.x; i < 512; i += 256) {
        const int lane = i >> 3, j = i & 7;
        const int n = g * 16 + (lane & 15);
        const int k = ks * 32 + (lane >> 4) * 8 + j;
        const float v = (k < K) ? src[(size_t)k * 256 + n] : 0.f;
        dst[((size_t)(g * KS + ks) * 64 + lane) * 8 + j] = __float2bfloat16(v);
    }
}

// ---------------------------------------------------------------------------
// K fragment swizzle (16B-chunk permutation).
__global__ __launch_bounds__(256) void kswz_kernel(
    const __hip_bfloat16* __restrict__ K, __hip_bfloat16* __restrict__ blob)
{
    const int c = blockIdx.x * 256 + threadIdx.x;
    const int lane = c & 63;
    const int s    = (c >> 6) & 7;
    const int kt   = c >> 9;
    const __hip_bfloat16* src =
        K + (size_t)(kt * 16 + (lane & 15)) * HD + s * 32 + (lane >> 4) * 8;
    *reinterpret_cast<uint4*>(blob + (size_t)c * 8) =
        *reinterpret_cast<const uint4*>(src);
}

// ---------------------------------------------------------------------------
// V fragment swizzle (LDS-tiled transpose), one 32-key tile per block.
__global__ __launch_bounds__(256) void vswz_kernel(
    const __hip_bfloat16* __restrict__ V, __hip_bfloat16* __restrict__ blob)
{
    __shared__ unsigned short s[32][264];
    const int jt  = blockIdx.x;
    const int tid = threadIdx.x;
    {
        const int row = tid >> 3;
        const int d0  = (tid & 7) * 32;
        const __hip_bfloat16* vp = V + (size_t)(jt * 32 + row) * HD + d0;
        #pragma unroll
        for (int i = 0; i < 4; ++i)
            *reinterpret_cast<uint4*>(&s[row][d0 + 8 * i]) =
                *reinterpret_cast<const uint4*>(vp + 8 * i);
    }
    __syncthreads();
    {
        const int w    = tid >> 6;
        const int lane = tid & 63;
        const int col  = lane & 15;
        const int quad = lane >> 4;
        #pragma unroll
        for (int i = 0; i < 4; ++i) {
            const int dt = w + i * 4;
            unsigned short tmp[8];
            #pragma unroll
            for (int j = 0; j < 8; ++j)
                tmp[j] = s[quad * 8 + j][dt * 16 + col];
            *reinterpret_cast<uint4*>(
                blob + ((size_t)(jt * 16 + dt) * 64 + lane) * 8) =
                *reinterpret_cast<uint4*>(tmp);
        }
    }
}

// ---------------------------------------------------------------------------
// Edge MFMA kernel: 64 edges/block, 512 threads (8 waves x 32-col strips).
__global__ __launch_bounds__(512, 4) void edge_mfma(
    const float* __restrict__ coords, const float* __restrict__ h,
    const float* __restrict__ ef,
    const int* __restrict__ src, const int* __restrict__ dst,
    const __hip_bfloat16* __restrict__ W1s, const float* __restrict__ b1,
    const __hip_bfloat16* __restrict__ W2s, const float* __restrict__ b2,
    const __hip_bfloat16* __restrict__ Wc1s, const float* __restrict__ bc1,
    const float* __restrict__ wc2v, const float* __restrict__ bc2,
    float* __restrict__ aggr, float* __restrict__ cnt, float* __restrict__ xsum)
{
    __shared__ unsigned short sX[64][XP];
    __shared__ float sXrel[64][3];
    __shared__ int   sDst[64];
    __shared__ float sRedW[8][64];

    const int tid  = threadIdx.x;
    const int lane = tid & 63;
    const int wave = tid >> 6;           // 0..7
    const int col  = lane & 15;
    const int quad = lane >> 4;
    const int e0   = blockIdx.x * 64;
    const int nb   = wave * 32;          // wave's 32-col strip base

    // gather h_src | h_dst (cols 0..511)
    for (int i = tid; i < 64 * 128; i += 512) {
        const int row = i >> 7, c4 = i & 127;
        const int node = (c4 < 64) ? src[e0 + row] : dst[e0 + row];
        const float4 v = *reinterpret_cast<const float4*>(
            &h[(size_t)node * HD + (c4 & 63) * 4]);
        ushort4 u = { f2bu(v.x), f2bu(v.y), f2bu(v.z), f2bu(v.w) };
        *reinterpret_cast<ushort4*>(&sX[row][c4 * 4]) = u;
    }
    // ef (cols 512..527)
    if (tid < 256) {
        const int row = tid >> 2, c = tid & 3;
        const float4 v = *reinterpret_cast<const float4*>(
            &ef[(size_t)(e0 + row) * EFD + c * 4]);
        ushort4 u = { f2bu(v.x), f2bu(v.y), f2bu(v.z), f2bu(v.w) };
        *reinterpret_cast<ushort4*>(&sX[row][512 + c * 4]) = u;
    }
    // rbf (cols 528..542), pad, xrel, dst
    if (tid < 64) {
        const int e = e0 + tid;
        const int s = src[e], d = dst[e];
        sDst[tid] = d;
        float d2 = 0.f;
        #pragma unroll
        for (int c = 0; c < 3; ++c) {
            const float xr = coords[s * 3 + c] - coords[d * 3 + c];
            sXrel[tid][c] = xr;
            d2 += xr * xr;
        }
        float sig = 1.0f;
        #pragma unroll
        for (int si = 0; si < NSIG; ++si) {
            sX[tid][528 + si] = f2bu(__expf(-d2 / sig));
            sig *= 1.5f;
        }
        sX[tid][543] = 0;
    }
    __syncthreads();

    f32x4 acc[4][2];

    // layer 1: 544 -> 256
    #pragma unroll
    for (int nt = 0; nt < 2; ++nt) {
        const float bv = b1[nb + nt * 16 + col];
        #pragma unroll
        for (int mt = 0; mt < 4; ++mt) acc[mt][nt] = { bv, bv, bv, bv };
    }
    mfma_gemm<4, 2>(&sX[0][0], XP, W1s + (size_t)(wave * 2) * 17 * 512, 17, lane, acc);
    __syncthreads();
    #pragma unroll
    for (int mt = 0; mt < 4; ++mt)
        #pragma unroll
        for (int nt = 0; nt < 2; ++nt)
            #pragma unroll
            for (int r = 0; r < 4; ++r)
                sX[mt * 16 + quad * 4 + r][nb + nt * 16 + col] =
                    f2bu(lrelu(acc[mt][nt][r]));
    __syncthreads();

    // layer 2: 256 -> 256 (msg)
    #pragma unroll
    for (int nt = 0; nt < 2; ++nt) {
        const float bv = b2[nb + nt * 16 + col];
        #pragma unroll
        for (int mt = 0; mt < 4; ++mt) acc[mt][nt] = { bv, bv, bv, bv };
    }
    mfma_gemm<4, 2>(&sX[0][0], XP, W2s + (size_t)(wave * 2) * 8 * 512, 8, lane, acc);
    __syncthreads();
    #pragma unroll
    for (int mt = 0; mt < 4; ++mt)
        #pragma unroll
        for (int nt = 0; nt < 2; ++nt)
            #pragma unroll
            for (int r = 0; r < 4; ++r) {
                const int row = mt * 16 + quad * 4 + r;
                const int n   = nb + nt * 16 + col;
                const float v = acc[mt][nt][r];
                atomicAdd(&aggr[(size_t)sDst[row] * HD + n], v);
                sX[row][n] = f2bu(v);
            }
    __syncthreads();

    // coords MLP: 256 -> 256 (lrelu) -> dot wc2
    #pragma unroll
    for (int nt = 0; nt < 2; ++nt) {
        const float bv = bc1[nb + nt * 16 + col];
        #pragma unroll
        for (int mt = 0; mt < 4; ++mt) acc[mt][nt] = { bv, bv, bv, bv };
    }
    mfma_gemm<4, 2>(&sX[0][0], XP, Wc1s + (size_t)(wave * 2) * 8 * 512, 8, lane, acc);
    float w2l[2];
    #pragma unroll
    for (int nt = 0; nt < 2; ++nt) w2l[nt] = wc2v[nb + nt * 16 + col];
    #pragma unroll
    for (int mt = 0; mt < 4; ++mt) {
        float pr[4] = { 0.f, 0.f, 0.f, 0.f };
        #pragma unroll
        for (int nt = 0; nt < 2; ++nt)
            #pragma unroll
            for (int r = 0; r < 4; ++r)
                pr[r] += lrelu(acc[mt][nt][r]) * w2l[nt];
        #pragma unroll
        for (int r = 0; r < 4; ++r) {
            #pragma unroll
            for (int off = 1; off < 16; off <<= 1) pr[r] += __shfl_xor(pr[r], off);
        }
        if (col == 0)
            #pragma unroll
            for (int r = 0; r < 4; ++r)
                sRedW[wave][mt * 16 + quad * 4 + r] = pr[r];
    }
    __syncthreads();
    if (tid < 64) {
        float p = bc2[0];
        #pragma unroll
        for (int w = 0; w < 8; ++w) p += sRedW[w][tid];
        const int d = sDst[tid];
        #pragma unroll
        for (int c = 0; c < 3; ++c)
            atomicAdd(&xsum[(size_t)d * 3 + c], sXrel[tid][c] * p);
        atomicAdd(&cnt[d], 1.0f);
    }
}

// ---------------------------------------------------------------------------
// Node MFMA kernel: 32 nodes/block (unchanged logic).
__global__ __launch_bounds__(256, 4) void node_mfma(
    const float* __restrict__ aggr, const float* __restrict__ cnt,
    const __hip_bfloat16* __restrict__ cross, const float* __restrict__ orig,
    const float* __restrict__ hfeat,
    const __hip_bfloat16* __restrict__ WN1s, const float* __restrict__ b1,
    const __hip_bfloat16* __restrict__ WN2s, const float* __restrict__ b2,
    float* __restrict__ out)
{
    __shared__ unsigned short sXn[32][XPN];
    __shared__ float sInv[32];

    const int tid  = threadIdx.x;
    const int lane = tid & 63;
    const int wave = tid >> 6;
    const int col  = lane & 15;
    const int quad = lane >> 4;
    const int r0   = blockIdx.x * 32;

    if (tid < 32) sInv[tid] = 1.f / fmaxf(cnt[r0 + tid], 1.f);
    __syncthreads();

    for (int i = tid; i < 32 * 64; i += 256) {
        const int row = i >> 6, c4 = i & 63;
        const float inv = sInv[row];
        const float4 v = *reinterpret_cast<const float4*>(
            &aggr[(size_t)(r0 + row) * HD + c4 * 4]);
        ushort4 u = { f2bu(v.x * inv), f2bu(v.y * inv), f2bu(v.z * inv), f2bu(v.w * inv) };
        *reinterpret_cast<ushort4*>(&sXn[row][c4 * 4]) = u;
    }
    for (int i = tid; i < 32 * 64; i += 256) {
        const int row = i >> 6, c4 = i & 63;
        const ushort4 u = *reinterpret_cast<const ushort4*>(
            &cross[(size_t)(r0 + row) * HD + c4 * 4]);
        *reinterpret_cast<ushort4*>(&sXn[row][256 + c4 * 4]) = u;
    }
    for (int i = tid; i < 32 * 16; i += 256) {
        const int row = i >> 4, c4 = i & 15;
        const float4 v = *reinterpret_cast<const float4*>(
            &orig[(size_t)(r0 + row) * ORIGD + c4 * 4]);
        ushort4 u = { f2bu(v.x), f2bu(v.y), f2bu(v.z), f2bu(v.w) };
        *reinterpret_cast<ushort4*>(&sXn[row][512 + c4 * 4]) = u;
    }
    __syncthreads();

    f32x4 acc[2][4];

    #pragma unroll
    for (int nt = 0; nt < 4; ++nt) {
        const float bv = b1[wave * 64 + nt * 16 + col];
        acc[0][nt] = { bv, bv, bv, bv };
        acc[1][nt] = { bv, bv, bv, bv };
    }
    mfma_gemm<2, 4>(&sXn[0][0], XPN, WN1s + (size_t)(wave * 4) * 18 * 512, 18, lane, acc);
    __syncthreads();
    #pragma unroll
    for (int mt = 0; mt < 2; ++mt)
        #pragma unroll
        for (int nt = 0; nt < 4; ++nt)
            #pragma unroll
            for (int r = 0; r < 4; ++r)
                sXn[mt * 16 + quad * 4 + r][wave * 64 + nt * 16 + col] =
                    f2bu(lrelu(acc[mt][nt][r]));
    __syncthreads();

    #pragma unroll
    for (int nt = 0; nt < 4; ++nt) {
        const float bv = b2[wave * 64 + nt * 16 + col];
        acc[0][nt] = { bv, bv, bv, bv };
        acc[1][nt] = { bv, bv, bv, bv };
    }
    mfma_gemm<2, 4>(&sXn[0][0], XPN, WN2s + (size_t)(wave * 4) * 8 * 512, 8, lane, acc);
    #pragma unroll
    for (int mt = 0; mt < 2; ++mt)
        #pragma unroll
        for (int nt = 0; nt < 4; ++nt)
            #pragma unroll
            for (int r = 0; r < 4; ++r) {
                const int g = r0 + mt * 16 + quad * 4 + r;
                const int n = wave * 64 + nt * 16 + col;
                out[(size_t)g * HD + n] =
                    0.5f * acc[mt][nt][r] + 0.5f * hfeat[(size_t)g * HD + n];
            }
}

// ---------------------------------------------------------------------------
__global__ __launch_bounds__(256, 4) void proj_mfma(
    const float* __restrict__ X, const __hip_bfloat16* __restrict__ Ws,
    __hip_bfloat16* __restrict__ out, int applyLrelu)
{
    __shared__ unsigned short sXp[32][XPP];
    const int tid  = threadIdx.x;
    const int lane = tid & 63;
    const int wave = tid >> 6;
    const int col  = lane & 15;
    const int quad = lane >> 4;
    const int r0   = blockIdx.x * 32;

    for (int i = tid; i < 32 * 64; i += 256) {
        const int row = i >> 6, c4 = i & 63;
        const float4 v = *reinterpret_cast<const float4*>(
            &X[(size_t)(r0 + row) * HD + c4 * 4]);
        ushort4 u = { f2bu(v.x), f2bu(v.y), f2bu(v.z), f2bu(v.w) };
        *reinterpret_cast<ushort4*>(&sXp[row][c4 * 4]) = u;
    }
    __syncthreads();

    f32x4 acc[2][4];
    #pragma unroll
    for (int nt = 0; nt < 4; ++nt) {
        acc[0][nt] = { 0.f, 0.f, 0.f, 0.f };
        acc[1][nt] = { 0.f, 0.f, 0.f, 0.f };
    }
    mfma_gemm<2, 4>(&sXp[0][0], XPP, Ws + (size_t)(wave * 4) * 8 * 512, 8, lane, acc);
    #pragma unroll
    for (int mt = 0; mt < 2; ++mt)
        #pragma unroll
        for (int nt = 0; nt < 4; ++nt)
            #pragma unroll
            for (int r = 0; r < 4; ++r) {
                float v = acc[mt][nt][r];
                if (applyLrelu) v = lrelu(v);
                out[(size_t)(r0 + mt * 16 + quad * 4 + r) * HD +
                    wave * 64 + nt * 16 + col] = __float2bfloat16(v);
            }
}

// ---------------------------------------------------------------------------
// Barrier-free MFMA flash attention partial. 32 q-rows/block (2 waves x 16).
// K/V fragments read DIRECTLY from the swizzled global blobs (coalesced 16B).
// Only per-wave LDS (P round-trip, mask tile) -> no __syncthreads in K-loop.
__global__ __launch_bounds__(128, 3) void attn_mfma(
    const __hip_bfloat16* __restrict__ Qb, const __hip_bfloat16* __restrict__ Kz,
    const __hip_bfloat16* __restrict__ Vz, const float* __restrict__ maskG,
    float* __restrict__ PO, float* __restrict__ PM, float* __restrict__ PL,
    int M, int chunkKeys, int transposed)
{
    __shared__ unsigned short sP[2][16][40];
    __shared__ float          sMask[2][16][36];

    const int tid  = threadIdx.x;
    const int lane = tid & 63;
    const int wave = tid >> 6;
    const int col  = lane & 15;
    const int quad = lane >> 4;
    const int R0   = blockIdx.x * 32;
    const int split = blockIdx.y;
    const int jbase = split * chunkKeys;

    bf16x8 qf[8];
    {
        const __hip_bfloat16* qp =
            Qb + (size_t)(R0 + wave * 16 + col) * HD + quad * 8;
        #pragma unroll
        for (int s = 0; s < 8; ++s)
            qf[s] = *reinterpret_cast<const bf16x8*>(qp + 32 * s);
    }

    f32x4 o[16];
    #pragma unroll
    for (int dt = 0; dt < 16; ++dt) { o[dt][0]=0.f; o[dt][1]=0.f; o[dt][2]=0.f; o[dt][3]=0.f; }
    float m[4], l[4];
    #pragma unroll
    for (int r = 0; r < 4; ++r) { m[r] = -INFINITY; l[r] = 0.f; }

    for (int jt = 0; jt < chunkKeys; jt += 32) {
        const int j0 = jbase + jt;

        // ---- stage mask tile per wave (wave-private LDS; no barrier) ----
        if (!transposed) {
            const int row = lane >> 2;
            const int c0  = (lane & 3) * 8;
            #pragma unroll
            for (int i = 0; i < 2; ++i)
                *reinterpret_cast<float4*>(&sMask[wave][row][c0 + 4 * i]) =
                    *reinterpret_cast<const float4*>(
                        &maskG[(size_t)(R0 + wave * 16 + row) * N_REC + j0 + c0 + 4 * i]);
        } else {
            const int key = lane >> 1;
            const int rb  = (lane & 1) * 8;
            float tmp[8];
            #pragma unroll
            for (int i = 0; i < 2; ++i)
                *reinterpret_cast<float4*>(&tmp[4 * i]) =
                    *reinterpret_cast<const float4*>(
                        &maskG[(size_t)(j0 + key) * N_REC + R0 + wave * 16 + rb + 4 * i]);
            #pragma unroll
            for (int u = 0; u < 8; ++u)
                sMask[wave][rb + u][key] = tmp[u];
        }

        // ---- S = Q K^T (fragments straight from global blob) ----
        const size_t jt16 = (size_t)(j0 >> 4);
        f32x4 sacc[2];
        sacc[0][0]=0.f; sacc[0][1]=0.f; sacc[0][2]=0.f; sacc[0][3]=0.f;
        sacc[1][0]=0.f; sacc[1][1]=0.f; sacc[1][2]=0.f; sacc[1][3]=0.f;
        #pragma unroll
        for (int t = 0; t < 2; ++t) {
            #pragma unroll
            for (int s = 0; s < 8; ++s) {
                bf16x8 kf = *reinterpret_cast<const bf16x8*>(
                    Kz + ((jt16 + t) * 8 + s) * 512 + lane * 8);
                sacc[t] = __builtin_amdgcn_mfma_f32_16x16x32_bf16(qf[s], kf, sacc[t], 0, 0, 0);
            }
        }

        // ---- online softmax ----
        float a[2][4];
        #pragma unroll
        for (int t = 0; t < 2; ++t)
            #pragma unroll
            for (int r = 0; r < 4; ++r) {
                const float mv = sMask[wave][quad * 4 + r][col + 16 * t];
                a[t][r] = mv * sacc[t][r] - 1000.f * (1.f - mv);
            }
        #pragma unroll
        for (int r = 0; r < 4; ++r) {
            float mx = fmaxf(a[0][r], a[1][r]);
            #pragma unroll
            for (int off = 1; off < 16; off <<= 1)
                mx = fmaxf(mx, __shfl_xor(mx, off));
            const float mn = fmaxf(m[r], mx);
            const float c  = __expf(m[r] - mn);
            m[r] = mn;
            const float p0 = __expf(a[0][r] - mn);
            const float p1 = __expf(a[1][r] - mn);
            sP[wave][quad * 4 + r][col]      = f2bu(p0);
            sP[wave][quad * 4 + r][col + 16] = f2bu(p1);
            float ps = p0 + p1;
            #pragma unroll
            for (int off = 1; off < 16; off <<= 1)
                ps += __shfl_xor(ps, off);
            l[r] = l[r] * c + ps;
            #pragma unroll
            for (int dt = 0; dt < 16; ++dt) o[dt][r] *= c;
        }

        // ---- O += P V (V fragments straight from global blob) ----
        const size_t jt32 = (size_t)(j0 >> 5);
        bf16x8 pf = *reinterpret_cast<const bf16x8*>(&sP[wave][col][quad * 8]);
        #pragma unroll
        for (int dt = 0; dt < 16; ++dt) {
            bf16x8 vf = *reinterpret_cast<const bf16x8*>(
                Vz + (jt32 * 16 + dt) * 512 + lane * 8);
            o[dt] = __builtin_amdgcn_mfma_f32_16x16x32_bf16(pf, vf, o[dt], 0, 0, 0);
        }
    }

    #pragma unroll
    for (int dt = 0; dt < 16; ++dt)
        #pragma unroll
        for (int r = 0; r < 4; ++r) {
            const int row = R0 + wave * 16 + quad * 4 + r;
            PO[((size_t)split * M + row) * HD + dt * 16 + col] = o[dt][r];
        }
    if (col == 0) {
        #pragma unroll
        for (int r = 0; r < 4; ++r) {
            const int row = R0 + wave * 16 + quad * 4 + r;
            PM[(size_t)split * M + row] = m[r];
            PL[(size_t)split * M + row] = l[r];
        }
    }
}

// ---------------------------------------------------------------------------
__global__ void attn_combine(
    const float* __restrict__ PO, const float* __restrict__ PM,
    const float* __restrict__ PL, __hip_bfloat16* __restrict__ Out,
    int M, int nchunks)
{
    const int idx = blockIdx.x * 256 + threadIdx.x;
    const int row = idx >> 8;
    float mmax = -INFINITY;
    for (int c = 0; c < nchunks; ++c) mmax = fmaxf(mmax, PM[(size_t)c * M + row]);
    float denom = 0.f, acc = 0.f;
    for (int c = 0; c < nchunks; ++c) {
        const float w = __expf(PM[(size_t)c * M + row] - mmax);
        denom += PL[(size_t)c * M + row] * w;
        acc   += PO[(size_t)c * M * HD + idx] * w;
    }
    Out[idx] = __float2bfloat16(acc / denom);
}

// ---------------------------------------------------------------------------
__global__ void coords_fin(
    const float* __restrict__ coords, const float* __restrict__ origc,
    const float* __restrict__ xsum, const float* __restrict__ cnt,
    float* __restrict__ out, int n)
{
    const int i = blockIdx.x * 256 + threadIdx.x;
    if (i >= n * 3) return;
    const int node = i / 3;
    const float inv = 1.f / fmaxf(cnt[node], 1.f);
    out[i] = 0.25f * origc[i] + 0.75f * coords[i] + xsum[i] * inv;
}

// ---------------------------------------------------------------------------
extern "C" void kernel_launch(void* const* d_in, const int* in_sizes, int n_in,
                              void* d_out, int out_size, void* d_ws, size_t ws_size,
                              hipStream_t stream)
{
    const float* coords_lig = (const float*)d_in[0];
    const float* h_lig      = (const float*)d_in[1];
    const float* orig_lig   = (const float*)d_in[2];
    const float* origc_lig  = (const float*)d_in[3];
    const float* coords_rec = (const float*)d_in[4];
    const float* h_rec      = (const float*)d_in[5];
    const float* orig_rec   = (const float*)d_in[6];
    const float* origc_rec  = (const float*)d_in[7];
    const float* mask       = (const float*)d_in[8];
    const float* lig_ef     = (const float*)d_in[9];
    const float* rec_ef     = (const float*)d_in[10];
    const int* lig_src = (const int*)d_in[11];
    const int* lig_dst = (const int*)d_in[12];
    const int* rec_src = (const int*)d_in[13];
    const int* rec_dst = (const int*)d_in[14];
    const float* le_w1 = (const float*)d_in[15];
    const float* le_b1 = (const float*)d_in[16];
    const float* le_w2 = (const float*)d_in[17];
    const float* le_b2 = (const float*)d_in[18];
    const float* re_w1 = (const float*)d_in[19];
    const float* re_b1 = (const float*)d_in[20];
    const float* re_w2 = (const float*)d_in[21];
    const float* re_b2 = (const float*)d_in[22];
    const float* aql_w = (const float*)d_in[23];
    const float* akl_w = (const float*)d_in[24];
    const float* avl_w = (const float*)d_in[25];
    const float* aqr_w = (const float*)d_in[26];
    const float* akr_w = (const float*)d_in[27];
    const float* avr_w = (const float*)d_in[28];
    const float* nl_w1 = (const float*)d_in[29];
    const float* nl_b1 = (const float*)d_in[30];
    const float* nl_w2 = (const float*)d_in[31];
    const float* nl_b2 = (const float*)d_in[32];
    const float* nr_w1 = (const float*)d_in[33];
    const float* nr_b1 = (const float*)d_in[34];
    const float* nr_w2 = (const float*)d_in[35];
    const float* nr_b2 = (const float*)d_in[36];
    const float* cl_w1 = (const float*)d_in[37];
    const float* cl_b1 = (const float*)d_in[38];
    const float* cl_w2 = (const float*)d_in[39];
    const float* cl_b2 = (const float*)d_in[40];
    const float* cr_w1 = (const float*)d_in[41];
    const float* cr_b1 = (const float*)d_in[42];
    const float* cr_w2 = (const float*)d_in[43];
    const float* cr_b2 = (const float*)d_in[44];

    float* out = (float*)d_out;
    float* wsf = (float*)d_ws;

    // ---- fp32 accumulator zone (zeroed) ----
    const size_t AGGRL = 0;
    const size_t AGGRR = AGGRL + (size_t)N_LIG * HD;
    const size_t CNTL  = AGGRR + (size_t)N_REC * HD;
    const size_t CNTR  = CNTL + N_LIG;
    const size_t XSUML = CNTR + N_REC;
    const size_t XSUMR = XSUML + (size_t)N_LIG * 3;
    const size_t ZEND  = XSUMR + (size_t)N_REC * 3;

    // ---- bf16 zone ----
    __hip_bfloat16* wsb = (__hip_bfloat16*)(wsf + ZEND);
    const size_t QL  = 0;
    const size_t KL  = QL + (size_t)N_LIG * HD;
    const size_t VL  = KL + (size_t)N_LIG * HD;
    const size_t QR  = VL + (size_t)N_LIG * HD;
    const size_t KR  = QR + (size_t)N_REC * HD;
    const size_t VR  = KR + (size_t)N_REC * HD;
    const size_t CRL = VR + (size_t)N_REC * HD;
    const size_t CRR = CRL + (size_t)N_LIG * HD;
    const size_t KZL = CRR + (size_t)N_REC * HD;
    const size_t VZL = KZL + (size_t)N_LIG * HD;
    const size_t KZR = VZL + (size_t)N_LIG * HD;
    const size_t VZR = KZR + (size_t)N_REC * HD;
    const size_t EW1SZ = (size_t)16 * 17 * 512;
    const size_t KW256 = (size_t)16 * 8 * 512;
    const size_t NW1SZ = (size_t)16 * 18 * 512;
    const size_t SW_EL1 = VZR + (size_t)N_REC * HD;
    const size_t SW_EL2 = SW_EL1 + EW1SZ;
    const size_t SW_EC1 = SW_EL2 + KW256;
    const size_t SW_NL1 = SW_EC1 + KW256;
    const size_t SW_NL2 = SW_NL1 + NW1SZ;
    const size_t SW_ER1 = SW_NL2 + KW256;
    const size_t SW_ER2 = SW_ER1 + EW1SZ;
    const size_t SW_EC1R = SW_ER2 + KW256;
    const size_t SW_NR1 = SW_EC1R + KW256;
    const size_t SW_NR2 = SW_NR1 + NW1SZ;
    const size_t SW_PQL = SW_NR2 + KW256;
    const size_t SW_PKL = SW_PQL + KW256;
    const size_t SW_PVL = SW_PKL + KW256;
    const size_t SW_PQR = SW_PVL + KW256;
    const size_t SW_PKR = SW_PQR + KW256;
    const size_t SW_PVR = SW_PKR + KW256;
    const size_t BF_END = SW_PVR + KW256;

    // ---- split-K partial zone (fp32), dynamic splits ----
    float* wsp = (float*)(wsb + ((BF_END + 1) & ~(size_t)1));
    const size_t baseBytes = (size_t)((char*)wsp - (char*)d_ws);
    int SL = 16, SR = 4;
    {
        const size_t poElems16 = (size_t)16 * N_LIG * HD;
        const size_t need16 = baseBytes +
            (poElems16 + 2 * (size_t)16 * N_LIG) * sizeof(float);
        if (ws_size < need16) { SL = 8; SR = 2; }
    }
    const size_t PO_ = 0;
    const size_t PM_ = PO_ + (size_t)SL * N_LIG * HD;
    const size_t PL_ = PM_ + (size_t)SL * N_LIG;

    const size_t O_XL = 0;
    const size_t O_HL = O_XL + (size_t)N_LIG * 3;
    const size_t O_XR = O_HL + (size_t)N_LIG * HD;
    const size_t O_HR = O_XR + (size_t)N_REC * 3;

    // 1) zero atomic accumulators
    zero_kernel<<<((int)ZEND + 255) / 256, 256, 0, stream>>>(wsf, (int)ZEND);

    // 2) weight swizzles
    wt_swz<<<16 * 17, 256, 0, stream>>>(le_w1, wsb + SW_EL1, EIN, 17);
    wt_swz<<<16 * 8,  256, 0, stream>>>(le_w2, wsb + SW_EL2, 256, 8);
    wt_swz<<<16 * 8,  256, 0, stream>>>(cl_w1, wsb + SW_EC1, 256, 8);
    wt_swz<<<16 * 18, 256, 0, stream>>>(nl_w1, wsb + SW_NL1, 576, 18);
    wt_swz<<<16 * 8,  256, 0, stream>>>(nl_w2, wsb + SW_NL2, 256, 8);
    wt_swz<<<16 * 17, 256, 0, stream>>>(re_w1, wsb + SW_ER1, EIN, 17);
    wt_swz<<<16 * 8,  256, 0, stream>>>(re_w2, wsb + SW_ER2, 256, 8);
    wt_swz<<<16 * 8,  256, 0, stream>>>(cr_w1, wsb + SW_EC1R, 256, 8);
    wt_swz<<<16 * 18, 256, 0, stream>>>(nr_w1, wsb + SW_NR1, 576, 18);
    wt_swz<<<16 * 8,  256, 0, stream>>>(nr_w2, wsb + SW_NR2, 256, 8);
    wt_swz<<<16 * 8,  256, 0, stream>>>(aql_w, wsb + SW_PQL, 256, 8);
    wt_swz<<<16 * 8,  256, 0, stream>>>(akl_w, wsb + SW_PKL, 256, 8);
    wt_swz<<<16 * 8,  256, 0, stream>>>(avl_w, wsb + SW_PVL, 256, 8);
    wt_swz<<<16 * 8,  256, 0, stream>>>(aqr_w, wsb + SW_PQR, 256, 8);
    wt_swz<<<16 * 8,  256, 0, stream>>>(akr_w, wsb + SW_PKR, 256, 8);
    wt_swz<<<16 * 8,  256, 0, stream>>>(avr_w, wsb + SW_PVR, 256, 8);

    // 3) edge MFMA kernels (64 edges/block)
    edge_mfma<<<E_LIG_N / 64, 512, 0, stream>>>(
        coords_lig, h_lig, lig_ef, lig_src, lig_dst,
        wsb + SW_EL1, le_b1, wsb + SW_EL2, le_b2, wsb + SW_EC1, cl_b1, cl_w2, cl_b2,
        wsf + AGGRL, wsf + CNTL, wsf + XSUML);
    edge_mfma<<<E_REC_N / 64, 512, 0, stream>>>(
        coords_rec, h_rec, rec_ef, rec_src, rec_dst,
        wsb + SW_ER1, re_b1, wsb + SW_ER2, re_b2, wsb + SW_EC1R, cr_b1, cr_w2, cr_b2,
        wsf + AGGRR, wsf + CNTR, wsf + XSUMR);

    // 4) projections -> bf16 (MFMA), then K/V fragment swizzles
    proj_mfma<<<N_LIG / 32, 256, 0, stream>>>(h_lig, wsb + SW_PQL, wsb + QL, 1);
    proj_mfma<<<N_LIG / 32, 256, 0, stream>>>(h_lig, wsb + SW_PKL, wsb + KL, 1);
    proj_mfma<<<N_LIG / 32, 256, 0, stream>>>(h_lig, wsb + SW_PVL, wsb + VL, 0);
    proj_mfma<<<N_REC / 32, 256, 0, stream>>>(h_rec, wsb + SW_PQR, wsb + QR, 1);
    proj_mfma<<<N_REC / 32, 256, 0, stream>>>(h_rec, wsb + SW_PKR, wsb + KR, 1);
    proj_mfma<<<N_REC / 32, 256, 0, stream>>>(h_rec, wsb + SW_PVR, wsb + VR, 0);
    kswz_kernel<<<N_LIG / 8, 256, 0, stream>>>(wsb + KL, wsb + KZL);
    kswz_kernel<<<N_REC / 8, 256, 0, stream>>>(wsb + KR, wsb + KZR);
    vswz_kernel<<<N_LIG / 32, 256, 0, stream>>>(wsb + VL, wsb + VZL);
    vswz_kernel<<<N_REC / 32, 256, 0, stream>>>(wsb + VR, wsb + VZR);

    // 5) barrier-free MFMA flash attention, split-K + combine
    {
        dim3 gl(N_LIG / 32, SL);
        attn_mfma<<<gl, 128, 0, stream>>>(wsb + QL, wsb + KZR, wsb + VZR, mask,
                                          wsp + PO_, wsp + PM_, wsp + PL_,
                                          N_LIG, N_REC / SL, 0);
        attn_combine<<<N_LIG, 256, 0, stream>>>(
            wsp + PO_, wsp + PM_, wsp + PL_, wsb + CRL, N_LIG, SL);

        dim3 gr(N_REC / 32, SR);
        attn_mfma<<<gr, 128, 0, stream>>>(wsb + QR, wsb + KZL, wsb + VZL, mask,
                                          wsp + PO_, wsp + PM_, wsp + PL_,
                                          N_REC, N_LIG / SR, 1);
        attn_combine<<<N_REC, 256, 0, stream>>>(
            wsp + PO_, wsp + PM_, wsp + PL_, wsb + CRR, N_REC, SR);
    }

    // 6) coordinate outputs
    coords_fin<<<(N_LIG * 3 + 255) / 256, 256, 0, stream>>>(
        coords_lig, origc_lig, wsf + XSUML, wsf + CNTL, out + O_XL, N_LIG);
    coords_fin<<<(N_REC * 3 + 255) / 256, 256, 0, stream>>>(
        coords_rec, origc_rec, wsf + XSUMR, wsf + CNTR, out + O_XR, N_REC);

    // 7) node MFMA kernels
    node_mfma<<<N_LIG / 32, 256, 0, stream>>>(
        wsf + AGGRL, wsf + CNTL, wsb + CRL, orig_lig, h_lig,
        wsb + SW_NL1, nl_b1, wsb + SW_NL2, nl_b2, out + O_HL);
    node_mfma<<<N_REC / 32, 256, 0, stream>>>(
        wsf + AGGRR, wsf + CNTR, wsb + CRR, orig_rec, h_rec,
        wsb + SW_NR1, nr_b1, wsb + SW_NR2, nr_b2, out + O_HR);

    (void)in_sizes; (void)n_in; (void)out_size;
}